// Round 15
// baseline (163.072 us; speedup 1.0000x reference)
//
#include <hip/hip_runtime.h>

#define NB 64
#define NN 100
#define DL 32
#define BN (NB * NN)  // 6400

typedef _Float16 f16x8 __attribute__((ext_vector_type(8)));
typedef float f32x4 __attribute__((ext_vector_type(4)));

static __device__ __forceinline__ float lrelu(float x) { return fmaxf(x, 0.1f * x); }
static __device__ __forceinline__ f32x4 ld4(const float* p) { return *(const f32x4*)p; }
static __device__ __forceinline__ float hsum4(f32x4 v) { return v[0] + v[1] + v[2] + v[3]; }

// Fused pre-pass. Blocks 0..1599: h = x@lin_w+lin_b (4 rows each) + U/V step 0
// (V f16). Tail blocks: 1600/1601 PW B-frag swizzle; 1602..1607 pre-swizzled
// f16 epilogue weights (w0n, w1n per step; ew0[1] U/V rows; ow transposed) --
// layout [c-group][lane][8] so k_edge reads 16B/lane coalesced f16x8.
__global__ __launch_bounds__(256) void k_pre(
    const float* __restrict__ x, const float* __restrict__ lw, const float* __restrict__ lb,
    const float* __restrict__ ew0, const float* __restrict__ eb0,
    const float* __restrict__ w1a, const float* __restrict__ w1b,
    const float* __restrict__ nw0a, const float* __restrict__ nw0b,
    const float* __restrict__ nw1a, const float* __restrict__ nw1b,
    const float* __restrict__ ew0b, const float* __restrict__ ow,
    float* __restrict__ h, float* __restrict__ U, _Float16* __restrict__ V,
    _Float16* __restrict__ PW, _Float16* __restrict__ W0H, _Float16* __restrict__ W1H,
    _Float16* __restrict__ EW0H, _Float16* __restrict__ OWH) {
    int blk = blockIdx.x;
    int t = threadIdx.x;
    if (blk >= 1600) {
        int job = blk - 1600;
        if (job < 2) {  // PW[step][kt][hf][lane][jj]
            const float* w1 = job ? w1b : w1a;
            _Float16* dst = PW + job * 4096;
#pragma unroll
            for (int u = 0; u < 16; ++u) {
                int idx = t * 16 + u;
                int jj = idx & 7, lane = (idx >> 3) & 63, hf = (idx >> 9) & 1, kt = idx >> 10;
                int c = hf * 32 + (lane >> 4) * 8 + jj;
                int k = kt * 16 + (lane & 15);
                dst[idx] = (_Float16)w1[c * 64 + k];
            }
        } else if (job < 4) {  // node-L0 weights: W0H[c4][lane][i] = w0n[(c4*8+i)*64+lane]
            int s = job - 2;
            const float* src = s ? nw0b : nw0a;
            _Float16* dst = W0H + s * 6144;
            for (int u = t; u < 6144; u += 256) {
                int i = u & 7, lane = (u >> 3) & 63, c4 = u >> 9;
                dst[u] = (_Float16)src[(c4 * 8 + i) * 64 + lane];
            }
        } else if (job < 6) {  // node-L1: W1H[g][k2][i] = w1n[((g>>2)*32+(g&3)*8+i)*32+k2]
            int s = job - 4;
            const float* src = s ? nw1b : nw1a;
            _Float16* dst = W1H + s * 2048;
            for (int u = t; u < 2048; u += 256) {
                int i = u & 7, k2 = (u >> 3) & 31, g = u >> 8;
                int c = (g >> 2) * 32 + (g & 3) * 8 + i;
                dst[u] = (_Float16)src[c * 32 + k2];
            }
        } else if (job == 6) {  // step-1 U/V weights: EW0H[g][lane][i] = ew0b[(g*8+i)*64+lane]
            for (int u = t; u < 4096; u += 256) {
                int i = u & 7, lane = (u >> 3) & 63, g = u >> 9;
                EW0H[u] = (_Float16)ew0b[(g * 8 + i) * 64 + lane];
            }
        } else {  // out weights transposed: OWH[lane*32+c] = ow[c*3+lane]
            if (t < 96) {
                int lane = t >> 5, c = t & 31;
                OWH[lane * 32 + c] = (_Float16)ow[c * 3 + lane];
            }
        }
        return;
    }
    __shared__ float xs[DL];
    __shared__ float hs[4][DL];
    int row0 = blk * 4;
    int b = row0 / NN;  // 4-row group never crosses a batch boundary (100 % 4 == 0)
    if (t < DL) xs[t] = x[b * DL + t];
    __syncthreads();
    if (t < 128) {
        int ni = t >> 5, c = t & 31;
        int n = (row0 + ni) % NN;
        float s = lb[n * DL + c];
#pragma unroll
        for (int cc = 0; cc < DL; ++cc) s += xs[cc] * lw[cc * 3200 + n * DL + c];
        hs[ni][c] = s;
        h[(row0 + ni) * DL + c] = s;
    }
    __syncthreads();
#pragma unroll
    for (int r = 0; r < 2; ++r) {
        int o = r * 256 + t;  // 0..511 : 4 rows x (64 U + 64 V)
        int ni = o >> 7, kw = o & 127;
        int which = kw >> 6, k = kw & 63;
        const float* wp = ew0 + (which ? DL * 64 : 0) + k;
        float s = which ? 0.f : eb0[k];
#pragma unroll
        for (int c = 0; c < DL; ++c) s += hs[ni][c] * wp[c * 64];
        if (which) V[(row0 + ni) * 64 + k] = (_Float16)s;
        else       U[(row0 + ni) * 64 + k] = s;
    }
}

// Per-wave edge+node step, ONE barrier. v23: epilogue weights pre-swizzled f16
// (24KB total -> fully L1-resident) replace R12's swn0 LDS staging. Releases
// BOTH caps at once: LDS 38.9K->13.3K, VGPR 88->~64 (staging loop gone), and
// cuts epilogue weight loads 96 scalar -> 12 coalesced f16x8 per matvec.
// Kept lessons: no min-waves bound (R4/R5 spill), opaque-pb anti-hoist (R7),
// packed-f16 P-build + f16 V (R6), LDS pwl not global (R9), 4-lane dist + ld4
// epilogue inputs (R10), setprio on MFMA cluster (R12).
template <int FINAL>
__global__ __launch_bounds__(256) void k_edge(
    const float* __restrict__ h, const float* __restrict__ U, const _Float16* __restrict__ V,
    const float* __restrict__ w0, const _Float16* __restrict__ PW,
    const float* __restrict__ b1,
    const _Float16* __restrict__ w0nh, const float* __restrict__ b0n,
    const _Float16* __restrict__ w1nh, const float* __restrict__ b1n,
    const _Float16* __restrict__ wAh, const float* __restrict__ bA,
    float* __restrict__ hout, float* __restrict__ Uo, _Float16* __restrict__ Vo,
    float* __restrict__ out) {
    __shared__ __align__(16) _Float16 pwl[4096];
    __shared__ float sdist[4][112];
    __shared__ __align__(16) float sxin[4][96];  // [0..31]=h_i, [32..95]=agg
    __shared__ __align__(16) float st0[4][64];
    __shared__ __align__(16) float sh2[4][32];

    int t = threadIdx.x;
    {  // stage W1 B-fragments once for the whole block
        const f16x8* srcp = (const f16x8*)PW;
        f16x8* dstp = (f16x8*)pwl;
        dstp[t] = srcp[t];
        dstp[t + 256] = srcp[t + 256];
    }
    int w = t >> 6, lane = t & 63, q = lane >> 4, kk = lane & 15;
    int bi = blockIdx.x * 4 + w;
    int b = bi / NN;

    // h_i -> LDS (wave-local; read later via broadcast in the node MLP)
    if (lane < 32) sxin[w][lane] = h[bi * DL + lane];

    // distances: 4 lanes per j (16 j per iter, 7 iters), 32B/lane coalesced,
    // 2-step shfl reduce. All sdist writes complete before the barrier below.
    {
        int g = lane >> 2, r = lane & 3;
        const float* hi = h + bi * DL + r * 8;
        f32x4 hi0 = ld4(hi), hi1 = ld4(hi + 4);
        const float* hb = h + b * NN * DL;
#pragma unroll
        for (int it = 0; it < 7; ++it) {
            int j = it * 16 + g;
            int jc = j < NN ? j : NN - 1;
            const float* hj = hb + jc * DL + r * 8;
            f32x4 d0 = hi0 - ld4(hj);
            f32x4 d1 = hi1 - ld4(hj + 4);
            f32x4 s4 = d0 * d0 + d1 * d1;
            float s = hsum4(s4);
            s += __shfl_xor(s, 1);
            s += __shfl_xor(s, 2);
            if (r == 0) sdist[w][j] = sqrtf(s + 1e-12f);
        }
    }

    int c0 = q * 8;  // this lane's channel base
    // u (U_i + b0 folded) and wd as packed f16 (8 VGPRs each)
    f16x8 ulo, uhi, wdlo, wdhi;
    {
        const float* Up = U + (size_t)bi * 64;
        f32x4 a0 = ld4(Up + c0), a1 = ld4(Up + c0 + 4);
        f32x4 a2 = ld4(Up + 32 + c0), a3 = ld4(Up + 36 + c0);
        const float* wd = w0 + 64 * 64;
        f32x4 d0 = ld4(wd + c0), d1 = ld4(wd + c0 + 4);
        f32x4 d2 = ld4(wd + 32 + c0), d3 = ld4(wd + 36 + c0);
#pragma unroll
        for (int i = 0; i < 4; ++i) {
            ulo[i] = (_Float16)a0[i];  ulo[i + 4] = (_Float16)a1[i];
            uhi[i] = (_Float16)a2[i];  uhi[i + 4] = (_Float16)a3[i];
            wdlo[i] = (_Float16)d0[i]; wdlo[i + 4] = (_Float16)d1[i];
            wdhi[i] = (_Float16)d2[i]; wdhi[i + 4] = (_Float16)d3[i];
        }
    }
    float b1k[4];
#pragma unroll
    for (int kt = 0; kt < 4; ++kt) b1k[kt] = b1[kt * 16 + kk];
    float m6 = (q == 0) ? 1.f : 0.f;  // tile 6: only rows 96..99 (q==0) valid

    const _Float16* Vb = V + (size_t)b * NN * 64;
    // prefetch tile 0 (j = kk < 100, no clamp); V rows are f16
    f16x8 vlo, vhi;
    {
        const _Float16* vr = Vb + kk * 64 + c0;
        vlo = *(const f16x8*)vr;
        vhi = *(const f16x8*)(vr + 32);
    }

    __syncthreads();  // pwl ready
    float dj = sdist[w][kk];

    float sacc[4] = {0.f, 0.f, 0.f, 0.f};
    unsigned pb = 0;  // opaque LDS byte-offset: re-defined each jt by the asm nop
#pragma unroll
    for (int jt = 0; jt < 7; ++jt) {
        // P build in packed f16: result is exactly this lane's A-fragments
        _Float16 djh = (_Float16)dj;
        f16x8 dj8;
#pragma unroll
        for (int i = 0; i < 8; ++i) dj8[i] = djh;
        f16x8 A0 = __builtin_elementwise_fma(dj8, wdlo, ulo + vlo);
        f16x8 A1 = __builtin_elementwise_fma(dj8, wdhi, uhi + vhi);
        A0 = __builtin_elementwise_max(A0, (_Float16)0.1f * A0);
        A1 = __builtin_elementwise_max(A1, (_Float16)0.1f * A1);

        if (jt < 6) {  // prefetch next tile into the SAME v regs (in-order issue)
            int j = (jt + 1) * 16 + kk;
            int jc = (jt == 5 && j >= NN) ? NN - 1 : j;
            const _Float16* vr = Vb + jc * 64 + c0;
            vlo = *(const f16x8*)vr;
            vhi = *(const f16x8*)(vr + 32);
            dj = sdist[w][j];
        }
        // Opaque base: compiler cannot CSE/hoist the 8 B-frag ds_reads across
        // jt iterations -> they stay inside this body (peak +8 regs, not +32).
        asm volatile("" : "+v"(pb));
        const _Float16* pB = (const _Float16*)((const char*)pwl + pb);
        __builtin_amdgcn_s_setprio(1);
#pragma unroll
        for (int kt = 0; kt < 4; ++kt) {
            f16x8 B0 = *(const f16x8*)&pB[(kt * 2 + 0) * 512 + lane * 8];
            f16x8 B1 = *(const f16x8*)&pB[(kt * 2 + 1) * 512 + lane * 8];
            f32x4 a = {0.f, 0.f, 0.f, 0.f};
            a = __builtin_amdgcn_mfma_f32_16x16x32_f16(A0, B0, a, 0, 0, 0);
            a = __builtin_amdgcn_mfma_f32_16x16x32_f16(A1, B1, a, 0, 0, 0);
            f32x4 s4 = a + b1k[kt];
            s4 = __builtin_elementwise_max(s4, 0.1f * s4);
            float hs = hsum4(s4);
            sacc[kt] += (jt == 6) ? hs * m6 : hs;  // mask rows j >= 100 on last tile
        }
        __builtin_amdgcn_s_setprio(0);
    }

    // agg[k]: reduce across q groups; col kk -> k = kt*16+kk
    {
        float ag[4];
#pragma unroll
        for (int kt = 0; kt < 4; ++kt) {
            float s = sacc[kt];
            s += __shfl_xor(s, 16);
            s += __shfl_xor(s, 32);
            ag[kt] = s;
        }
        if (lane < 16) {
#pragma unroll
            for (int kt = 0; kt < 4; ++kt) sxin[w][32 + kt * 16 + lane] = ag[kt];
        }
    }

    // node MLP layer 0: lane = output k; 12 coalesced f16x8 weight loads
    // (w0nh[c4][lane][8], 16B/lane), L1-resident; ld4 LDS inputs
    {
        float sa = 0.f, sb = 0.f, sc = 0.f, sd = 0.f;
#pragma unroll
        for (int c4 = 0; c4 < 12; ++c4) {
            f16x8 wv = *(const f16x8*)&w0nh[(c4 * 64 + lane) * 8];
            f32x4 x0 = ld4(&sxin[w][c4 * 8]);
            f32x4 x1 = ld4(&sxin[w][c4 * 8 + 4]);
            sa += x0[0] * (float)wv[0]; sb += x0[1] * (float)wv[1];
            sc += x0[2] * (float)wv[2]; sd += x0[3] * (float)wv[3];
            sa += x1[0] * (float)wv[4]; sb += x1[1] * (float)wv[5];
            sc += x1[2] * (float)wv[6]; sd += x1[3] * (float)wv[7];
        }
        st0[w][lane] = lrelu((sa + sb) + (sc + sd) + b0n[lane]);
    }
    // node MLP layer 1: k = lane&31, half p = lane>>5; 4 f16x8 weight loads
    {
        int k2 = lane & 31, p = lane >> 5;
        float sa = 0.f, sb = 0.f, sc = 0.f, sd = 0.f;
#pragma unroll
        for (int c8 = 0; c8 < 4; ++c8) {
            f16x8 wv = *(const f16x8*)&w1nh[((p * 4 + c8) * 32 + k2) * 8];
            f32x4 x0 = ld4(&st0[w][p * 32 + c8 * 8]);
            f32x4 x1 = ld4(&st0[w][p * 32 + c8 * 8 + 4]);
            sa += x0[0] * (float)wv[0]; sb += x0[1] * (float)wv[1];
            sc += x0[2] * (float)wv[2]; sd += x0[3] * (float)wv[3];
            sa += x1[0] * (float)wv[4]; sb += x1[1] * (float)wv[5];
            sc += x1[2] * (float)wv[6]; sd += x1[3] * (float)wv[7];
        }
        float s = (sa + sb) + (sc + sd);
        s += __shfl_xor(s, 32);
        if (lane < 32) {
            float hv = lrelu(s + b1n[lane]);
            sh2[w][lane] = hv;
            if (!FINAL) hout[bi * DL + lane] = hv;
        }
    }

    if (FINAL) {
        if (lane < 3) {  // OWH[lane*32+c]: 4 f16x8 per lane
            float s = bA[lane];
#pragma unroll
            for (int c8 = 0; c8 < 4; ++c8) {
                f16x8 wv = *(const f16x8*)&wAh[(lane * 4 + c8) * 8];
                f32x4 x0 = ld4(&sh2[w][c8 * 8]);
                f32x4 x1 = ld4(&sh2[w][c8 * 8 + 4]);
                s += x0[0] * (float)wv[0] + x0[1] * (float)wv[1] +
                     x0[2] * (float)wv[2] + x0[3] * (float)wv[3] +
                     x1[0] * (float)wv[4] + x1[1] * (float)wv[5] +
                     x1[2] * (float)wv[6] + x1[3] * (float)wv[7];
            }
            out[bi * 3 + lane] = tanhf(s);
        }
    } else {  // U/V next step: EW0H groups 0..3 = U rows, 4..7 = V rows; V f16
        float su = bA[lane], sv = 0.f;
#pragma unroll
        for (int c4 = 0; c4 < 4; ++c4) {
            f16x8 wu = *(const f16x8*)&wAh[(c4 * 64 + lane) * 8];
            f16x8 wv2 = *(const f16x8*)&wAh[((4 + c4) * 64 + lane) * 8];
            f32x4 x0 = ld4(&sh2[w][c4 * 8]);
            f32x4 x1 = ld4(&sh2[w][c4 * 8 + 4]);
            su += x0[0] * (float)wu[0] + x0[1] * (float)wu[1] +
                  x0[2] * (float)wu[2] + x0[3] * (float)wu[3] +
                  x1[0] * (float)wu[4] + x1[1] * (float)wu[5] +
                  x1[2] * (float)wu[6] + x1[3] * (float)wu[7];
            sv += x0[0] * (float)wv2[0] + x0[1] * (float)wv2[1] +
                  x0[2] * (float)wv2[2] + x0[3] * (float)wv2[3] +
                  x1[0] * (float)wv2[4] + x1[1] * (float)wv2[5] +
                  x1[2] * (float)wv2[6] + x1[3] * (float)wv2[7];
        }
        Uo[bi * 64 + lane] = su;
        Vo[bi * 64 + lane] = (_Float16)sv;
    }
}

extern "C" void kernel_launch(void* const* d_in, const int* in_sizes, int n_in,
                              void* d_out, int out_size, void* d_ws, size_t ws_size,
                              hipStream_t stream) {
    const float* x     = (const float*)d_in[0];
    const float* lin_w = (const float*)d_in[1];
    const float* lin_b = (const float*)d_in[2];
    const float* ew0[2] = {(const float*)d_in[3],  (const float*)d_in[11]};
    const float* eb0[2] = {(const float*)d_in[4],  (const float*)d_in[12]};
    const float* ew1[2] = {(const float*)d_in[5],  (const float*)d_in[13]};
    const float* eb1[2] = {(const float*)d_in[6],  (const float*)d_in[14]};
    const float* nw0[2] = {(const float*)d_in[7],  (const float*)d_in[15]};
    const float* nb0[2] = {(const float*)d_in[8],  (const float*)d_in[16]};
    const float* nw1[2] = {(const float*)d_in[9],  (const float*)d_in[17]};
    const float* nb1[2] = {(const float*)d_in[10], (const float*)d_in[18]};
    const float* ow = (const float*)d_in[19];
    const float* ob = (const float*)d_in[20];
    float* out = (float*)d_out;

    float* h    = (float*)d_ws;               // 6400 x 32 f32
    float* h2   = h + 204800;                 // 6400 x 32 f32
    float* U    = h2 + 204800;                // 6400 x 64 f32
    float* U2   = U + 409600;                 // 6400 x 64 f32
    _Float16* V  = (_Float16*)(U2 + 409600);  // 6400 x 64 f16
    _Float16* V2 = V + 409600;                // 6400 x 64 f16
    _Float16* PW = V2 + 409600;               // 2 x 4096 f16
    _Float16* W0H  = PW + 8192;               // 2 x 6144 f16 (node-L0, swizzled)
    _Float16* W1H  = W0H + 12288;             // 2 x 2048 f16 (node-L1, swizzled)
    _Float16* EW0H = W1H + 4096;              // 4096 f16 (step-1 U/V, swizzled)
    _Float16* OWH  = EW0H + 4096;             // 96 f16 (out, transposed)

    k_pre<<<1608, 256, 0, stream>>>(x, lin_w, lin_b, ew0[0], eb0[0], ew1[0], ew1[1],
                                    nw0[0], nw0[1], nw1[0], nw1[1], ew0[1], ow,
                                    h, U, V, PW, W0H, W1H, EW0H, OWH);
    k_edge<0><<<1600, 256, 0, stream>>>(h, U, V, ew0[0], PW, eb1[0],
                                        W0H, nb0[0], W1H, nb1[0],
                                        EW0H, eb0[1], h2, U2, V2, nullptr);
    k_edge<1><<<1600, 256, 0, stream>>>(h2, U2, V2, ew0[1], PW + 4096, eb1[1],
                                        W0H + 6144, nb0[1], W1H + 2048, nb1[1],
                                        OWH, ob, nullptr, nullptr, nullptr, out);
}

// Round 16
// 157.626 us; speedup vs baseline: 1.0345x; 1.0345x over previous
//
#include <hip/hip_runtime.h>

#define NB 64
#define NN 100
#define DL 32
#define BN (NB * NN)  // 6400

typedef _Float16 f16x8 __attribute__((ext_vector_type(8)));
typedef float f32x4 __attribute__((ext_vector_type(4)));

static __device__ __forceinline__ float lrelu(float x) { return fmaxf(x, 0.1f * x); }
static __device__ __forceinline__ f32x4 ld4(const float* p) { return *(const f32x4*)p; }
static __device__ __forceinline__ float hsum4(f32x4 v) { return v[0] + v[1] + v[2] + v[3]; }

// Fused pre-pass. Blocks 0..1599: h = x@lin_w+lin_b (4 rows each) + U/V step 0
// (V f16). Tail blocks: 1600/1601 PW B-frag swizzle; 1602..1607 pre-swizzled
// f16 epilogue weights (w0n, w1n per step; ew0[1] U/V rows; ow transposed) --
// layout [c-group][lane][8] so k_edge reads 16B/lane coalesced f16x8.
__global__ __launch_bounds__(256) void k_pre(
    const float* __restrict__ x, const float* __restrict__ lw, const float* __restrict__ lb,
    const float* __restrict__ ew0, const float* __restrict__ eb0,
    const float* __restrict__ w1a, const float* __restrict__ w1b,
    const float* __restrict__ nw0a, const float* __restrict__ nw0b,
    const float* __restrict__ nw1a, const float* __restrict__ nw1b,
    const float* __restrict__ ew0b, const float* __restrict__ ow,
    float* __restrict__ h, float* __restrict__ U, _Float16* __restrict__ V,
    _Float16* __restrict__ PW, _Float16* __restrict__ W0H, _Float16* __restrict__ W1H,
    _Float16* __restrict__ EW0H, _Float16* __restrict__ OWH) {
    int blk = blockIdx.x;
    int t = threadIdx.x;
    if (blk >= 1600) {
        int job = blk - 1600;
        if (job < 2) {  // PW[step][kt][hf][lane][jj]
            const float* w1 = job ? w1b : w1a;
            _Float16* dst = PW + job * 4096;
#pragma unroll
            for (int u = 0; u < 16; ++u) {
                int idx = t * 16 + u;
                int jj = idx & 7, lane = (idx >> 3) & 63, hf = (idx >> 9) & 1, kt = idx >> 10;
                int c = hf * 32 + (lane >> 4) * 8 + jj;
                int k = kt * 16 + (lane & 15);
                dst[idx] = (_Float16)w1[c * 64 + k];
            }
        } else if (job < 4) {  // node-L0 weights: W0H[c4][lane][i] = w0n[(c4*8+i)*64+lane]
            int s = job - 2;
            const float* src = s ? nw0b : nw0a;
            _Float16* dst = W0H + s * 6144;
            for (int u = t; u < 6144; u += 256) {
                int i = u & 7, lane = (u >> 3) & 63, c4 = u >> 9;
                dst[u] = (_Float16)src[(c4 * 8 + i) * 64 + lane];
            }
        } else if (job < 6) {  // node-L1: W1H[g][k2][i] = w1n[((g>>2)*32+(g&3)*8+i)*32+k2]
            int s = job - 4;
            const float* src = s ? nw1b : nw1a;
            _Float16* dst = W1H + s * 2048;
            for (int u = t; u < 2048; u += 256) {
                int i = u & 7, k2 = (u >> 3) & 31, g = u >> 8;
                int c = (g >> 2) * 32 + (g & 3) * 8 + i;
                dst[u] = (_Float16)src[c * 32 + k2];
            }
        } else if (job == 6) {  // step-1 U/V weights: EW0H[g][lane][i] = ew0b[(g*8+i)*64+lane]
            for (int u = t; u < 4096; u += 256) {
                int i = u & 7, lane = (u >> 3) & 63, g = u >> 9;
                EW0H[u] = (_Float16)ew0b[(g * 8 + i) * 64 + lane];
            }
        } else {  // out weights transposed: OWH[lane*32+c] = ow[c*3+lane]
            if (t < 96) {
                int lane = t >> 5, c = t & 31;
                OWH[lane * 32 + c] = (_Float16)ow[c * 3 + lane];
            }
        }
        return;
    }
    __shared__ float xs[DL];
    __shared__ float hs[4][DL];
    int row0 = blk * 4;
    int b = row0 / NN;  // 4-row group never crosses a batch boundary (100 % 4 == 0)
    if (t < DL) xs[t] = x[b * DL + t];
    __syncthreads();
    if (t < 128) {
        int ni = t >> 5, c = t & 31;
        int n = (row0 + ni) % NN;
        float s = lb[n * DL + c];
#pragma unroll
        for (int cc = 0; cc < DL; ++cc) s += xs[cc] * lw[cc * 3200 + n * DL + c];
        hs[ni][c] = s;
        h[(row0 + ni) * DL + c] = s;
    }
    __syncthreads();
#pragma unroll
    for (int r = 0; r < 2; ++r) {
        int o = r * 256 + t;  // 0..511 : 4 rows x (64 U + 64 V)
        int ni = o >> 7, kw = o & 127;
        int which = kw >> 6, k = kw & 63;
        const float* wp = ew0 + (which ? DL * 64 : 0) + k;
        float s = which ? 0.f : eb0[k];
#pragma unroll
        for (int c = 0; c < DL; ++c) s += hs[ni][c] * wp[c * 64];
        if (which) V[(row0 + ni) * 64 + k] = (_Float16)s;
        else       U[(row0 + ni) * 64 + k] = s;
    }
}

// Per-wave edge+node step, ONE barrier. v25 = R12's mechanism (LDS-staged
// node-L0 weights) at R15's footprint (f16, pre-swizzled): swn0h is 12.3KB
// instead of f32's 24.6KB, so LDS = 25.3KB -> 6 blocks/CU, and the f16 staging
// loop's in-flight state (3 f16x8 = 12 regs) should let VGPR return to ~64
// (R10's no-staging level) -> both caps released -> full grid co-resident.
// w1n/wA stay global f16 (12KB, L1-resident). f16-weight numerics verified by
// R15 (absmax unchanged 0.00390625).
// Kept lessons: no min-waves bound (R4/R5 spill), opaque-pb anti-hoist (R7),
// packed-f16 P-build + f16 V (R6), LDS pwl not global (R9), 4-lane dist + ld4
// epilogue inputs (R10), setprio on MFMA cluster (R12).
template <int FINAL>
__global__ __launch_bounds__(256) void k_edge(
    const float* __restrict__ h, const float* __restrict__ U, const _Float16* __restrict__ V,
    const float* __restrict__ w0, const _Float16* __restrict__ PW,
    const float* __restrict__ b1,
    const _Float16* __restrict__ w0nh, const float* __restrict__ b0n,
    const _Float16* __restrict__ w1nh, const float* __restrict__ b1n,
    const _Float16* __restrict__ wAh, const float* __restrict__ bA,
    float* __restrict__ hout, float* __restrict__ Uo, _Float16* __restrict__ Vo,
    float* __restrict__ out) {
    __shared__ __align__(16) _Float16 pwl[4096];
    __shared__ __align__(16) _Float16 swn0h[6144];  // 12.3 KB f16 node-L0 weights
    __shared__ float sdist[4][112];
    __shared__ __align__(16) float sxin[4][96];  // [0..31]=h_i, [32..95]=agg
    __shared__ __align__(16) float st0[4][64];
    __shared__ __align__(16) float sh2[4][32];

    int t = threadIdx.x;
    {  // stage W1 B-fragments + f16 node-L0 weights once for the whole block
        const f16x8* srcp = (const f16x8*)PW;
        f16x8* dstp = (f16x8*)pwl;
        dstp[t] = srcp[t];
        dstp[t + 256] = srcp[t + 256];
        const f16x8* s0 = (const f16x8*)w0nh;
        f16x8* d0 = (f16x8*)swn0h;
        d0[t] = s0[t];
        d0[t + 256] = s0[t + 256];
        d0[t + 512] = s0[t + 512];
    }
    int w = t >> 6, lane = t & 63, q = lane >> 4, kk = lane & 15;
    int bi = blockIdx.x * 4 + w;
    int b = bi / NN;

    // h_i -> LDS (wave-local; read later via broadcast in the node MLP)
    if (lane < 32) sxin[w][lane] = h[bi * DL + lane];

    // distances: 4 lanes per j (16 j per iter, 7 iters), 32B/lane coalesced,
    // 2-step shfl reduce. All sdist writes complete before the barrier below.
    {
        int g = lane >> 2, r = lane & 3;
        const float* hi = h + bi * DL + r * 8;
        f32x4 hi0 = ld4(hi), hi1 = ld4(hi + 4);
        const float* hb = h + b * NN * DL;
#pragma unroll
        for (int it = 0; it < 7; ++it) {
            int j = it * 16 + g;
            int jc = j < NN ? j : NN - 1;
            const float* hj = hb + jc * DL + r * 8;
            f32x4 d0 = hi0 - ld4(hj);
            f32x4 d1 = hi1 - ld4(hj + 4);
            f32x4 s4 = d0 * d0 + d1 * d1;
            float s = hsum4(s4);
            s += __shfl_xor(s, 1);
            s += __shfl_xor(s, 2);
            if (r == 0) sdist[w][j] = sqrtf(s + 1e-12f);
        }
    }

    int c0 = q * 8;  // this lane's channel base
    // u (U_i + b0 folded) and wd as packed f16 (8 VGPRs each)
    f16x8 ulo, uhi, wdlo, wdhi;
    {
        const float* Up = U + (size_t)bi * 64;
        f32x4 a0 = ld4(Up + c0), a1 = ld4(Up + c0 + 4);
        f32x4 a2 = ld4(Up + 32 + c0), a3 = ld4(Up + 36 + c0);
        const float* wd = w0 + 64 * 64;
        f32x4 d0 = ld4(wd + c0), d1 = ld4(wd + c0 + 4);
        f32x4 d2 = ld4(wd + 32 + c0), d3 = ld4(wd + 36 + c0);
#pragma unroll
        for (int i = 0; i < 4; ++i) {
            ulo[i] = (_Float16)a0[i];  ulo[i + 4] = (_Float16)a1[i];
            uhi[i] = (_Float16)a2[i];  uhi[i + 4] = (_Float16)a3[i];
            wdlo[i] = (_Float16)d0[i]; wdlo[i + 4] = (_Float16)d1[i];
            wdhi[i] = (_Float16)d2[i]; wdhi[i + 4] = (_Float16)d3[i];
        }
    }
    float b1k[4];
#pragma unroll
    for (int kt = 0; kt < 4; ++kt) b1k[kt] = b1[kt * 16 + kk];
    float m6 = (q == 0) ? 1.f : 0.f;  // tile 6: only rows 96..99 (q==0) valid

    const _Float16* Vb = V + (size_t)b * NN * 64;
    // prefetch tile 0 (j = kk < 100, no clamp); V rows are f16
    f16x8 vlo, vhi;
    {
        const _Float16* vr = Vb + kk * 64 + c0;
        vlo = *(const f16x8*)vr;
        vhi = *(const f16x8*)(vr + 32);
    }

    __syncthreads();  // pwl + swn0h ready
    float dj = sdist[w][kk];

    float sacc[4] = {0.f, 0.f, 0.f, 0.f};
    unsigned pb = 0;  // opaque LDS byte-offset: re-defined each jt by the asm nop
#pragma unroll
    for (int jt = 0; jt < 7; ++jt) {
        // P build in packed f16: result is exactly this lane's A-fragments
        _Float16 djh = (_Float16)dj;
        f16x8 dj8;
#pragma unroll
        for (int i = 0; i < 8; ++i) dj8[i] = djh;
        f16x8 A0 = __builtin_elementwise_fma(dj8, wdlo, ulo + vlo);
        f16x8 A1 = __builtin_elementwise_fma(dj8, wdhi, uhi + vhi);
        A0 = __builtin_elementwise_max(A0, (_Float16)0.1f * A0);
        A1 = __builtin_elementwise_max(A1, (_Float16)0.1f * A1);

        if (jt < 6) {  // prefetch next tile into the SAME v regs (in-order issue)
            int j = (jt + 1) * 16 + kk;
            int jc = (jt == 5 && j >= NN) ? NN - 1 : j;
            const _Float16* vr = Vb + jc * 64 + c0;
            vlo = *(const f16x8*)vr;
            vhi = *(const f16x8*)(vr + 32);
            dj = sdist[w][j];
        }
        // Opaque base: compiler cannot CSE/hoist the 8 B-frag ds_reads across
        // jt iterations -> they stay inside this body (peak +8 regs, not +32).
        asm volatile("" : "+v"(pb));
        const _Float16* pB = (const _Float16*)((const char*)pwl + pb);
        __builtin_amdgcn_s_setprio(1);
#pragma unroll
        for (int kt = 0; kt < 4; ++kt) {
            f16x8 B0 = *(const f16x8*)&pB[(kt * 2 + 0) * 512 + lane * 8];
            f16x8 B1 = *(const f16x8*)&pB[(kt * 2 + 1) * 512 + lane * 8];
            f32x4 a = {0.f, 0.f, 0.f, 0.f};
            a = __builtin_amdgcn_mfma_f32_16x16x32_f16(A0, B0, a, 0, 0, 0);
            a = __builtin_amdgcn_mfma_f32_16x16x32_f16(A1, B1, a, 0, 0, 0);
            f32x4 s4 = a + b1k[kt];
            s4 = __builtin_elementwise_max(s4, 0.1f * s4);
            float hs = hsum4(s4);
            sacc[kt] += (jt == 6) ? hs * m6 : hs;  // mask rows j >= 100 on last tile
        }
        __builtin_amdgcn_s_setprio(0);
    }

    // agg[k]: reduce across q groups; col kk -> k = kt*16+kk
    {
        float ag[4];
#pragma unroll
        for (int kt = 0; kt < 4; ++kt) {
            float s = sacc[kt];
            s += __shfl_xor(s, 16);
            s += __shfl_xor(s, 32);
            ag[kt] = s;
        }
        if (lane < 16) {
#pragma unroll
            for (int kt = 0; kt < 4; ++kt) sxin[w][32 + kt * 16 + lane] = ag[kt];
        }
    }

    // node MLP layer 0: lane = output k; 12 LDS f16x8 weight reads (16B/lane,
    // conflict-free -- same pattern as pwl, measured 0 conflicts); ld4 inputs
    {
        float sa = 0.f, sb = 0.f, sc = 0.f, sd = 0.f;
#pragma unroll
        for (int c4 = 0; c4 < 12; ++c4) {
            f16x8 wv = *(const f16x8*)&swn0h[(c4 * 64 + lane) * 8];
            f32x4 x0 = ld4(&sxin[w][c4 * 8]);
            f32x4 x1 = ld4(&sxin[w][c4 * 8 + 4]);
            sa += x0[0] * (float)wv[0]; sb += x0[1] * (float)wv[1];
            sc += x0[2] * (float)wv[2]; sd += x0[3] * (float)wv[3];
            sa += x1[0] * (float)wv[4]; sb += x1[1] * (float)wv[5];
            sc += x1[2] * (float)wv[6]; sd += x1[3] * (float)wv[7];
        }
        st0[w][lane] = lrelu((sa + sb) + (sc + sd) + b0n[lane]);
    }
    // node MLP layer 1: k = lane&31, half p = lane>>5; 4 f16x8 weight loads
    // (global f16: w1n+wA = 12KB total, L1-resident)
    {
        int k2 = lane & 31, p = lane >> 5;
        float sa = 0.f, sb = 0.f, sc = 0.f, sd = 0.f;
#pragma unroll
        for (int c8 = 0; c8 < 4; ++c8) {
            f16x8 wv = *(const f16x8*)&w1nh[((p * 4 + c8) * 32 + k2) * 8];
            f32x4 x0 = ld4(&st0[w][p * 32 + c8 * 8]);
            f32x4 x1 = ld4(&st0[w][p * 32 + c8 * 8 + 4]);
            sa += x0[0] * (float)wv[0]; sb += x0[1] * (float)wv[1];
            sc += x0[2] * (float)wv[2]; sd += x0[3] * (float)wv[3];
            sa += x1[0] * (float)wv[4]; sb += x1[1] * (float)wv[5];
            sc += x1[2] * (float)wv[6]; sd += x1[3] * (float)wv[7];
        }
        float s = (sa + sb) + (sc + sd);
        s += __shfl_xor(s, 32);
        if (lane < 32) {
            float hv = lrelu(s + b1n[lane]);
            sh2[w][lane] = hv;
            if (!FINAL) hout[bi * DL + lane] = hv;
        }
    }

    if (FINAL) {
        if (lane < 3) {  // OWH[lane*32+c]: 4 f16x8 per lane
            float s = bA[lane];
#pragma unroll
            for (int c8 = 0; c8 < 4; ++c8) {
                f16x8 wv = *(const f16x8*)&wAh[(lane * 4 + c8) * 8];
                f32x4 x0 = ld4(&sh2[w][c8 * 8]);
                f32x4 x1 = ld4(&sh2[w][c8 * 8 + 4]);
                s += x0[0] * (float)wv[0] + x0[1] * (float)wv[1] +
                     x0[2] * (float)wv[2] + x0[3] * (float)wv[3] +
                     x1[0] * (float)wv[4] + x1[1] * (float)wv[5] +
                     x1[2] * (float)wv[6] + x1[3] * (float)wv[7];
            }
            out[bi * 3 + lane] = tanhf(s);
        }
    } else {  // U/V next step: EW0H groups 0..3 = U rows, 4..7 = V rows; V f16
        float su = bA[lane], sv = 0.f;
#pragma unroll
        for (int c4 = 0; c4 < 4; ++c4) {
            f16x8 wu = *(const f16x8*)&wAh[(c4 * 64 + lane) * 8];
            f16x8 wv2 = *(const f16x8*)&wAh[((4 + c4) * 64 + lane) * 8];
            f32x4 x0 = ld4(&sh2[w][c4 * 8]);
            f32x4 x1 = ld4(&sh2[w][c4 * 8 + 4]);
            su += x0[0] * (float)wu[0] + x0[1] * (float)wu[1] +
                  x0[2] * (float)wu[2] + x0[3] * (float)wu[3] +
                  x1[0] * (float)wu[4] + x1[1] * (float)wu[5] +
                  x1[2] * (float)wu[6] + x1[3] * (float)wu[7];
            sv += x0[0] * (float)wv2[0] + x0[1] * (float)wv2[1] +
                  x0[2] * (float)wv2[2] + x0[3] * (float)wv2[3] +
                  x1[0] * (float)wv2[4] + x1[1] * (float)wv2[5] +
                  x1[2] * (float)wv2[6] + x1[3] * (float)wv2[7];
        }
        Uo[bi * 64 + lane] = su;
        Vo[bi * 64 + lane] = (_Float16)sv;
    }
}

extern "C" void kernel_launch(void* const* d_in, const int* in_sizes, int n_in,
                              void* d_out, int out_size, void* d_ws, size_t ws_size,
                              hipStream_t stream) {
    const float* x     = (const float*)d_in[0];
    const float* lin_w = (const float*)d_in[1];
    const float* lin_b = (const float*)d_in[2];
    const float* ew0[2] = {(const float*)d_in[3],  (const float*)d_in[11]};
    const float* eb0[2] = {(const float*)d_in[4],  (const float*)d_in[12]};
    const float* ew1[2] = {(const float*)d_in[5],  (const float*)d_in[13]};
    const float* eb1[2] = {(const float*)d_in[6],  (const float*)d_in[14]};
    const float* nw0[2] = {(const float*)d_in[7],  (const float*)d_in[15]};
    const float* nb0[2] = {(const float*)d_in[8],  (const float*)d_in[16]};
    const float* nw1[2] = {(const float*)d_in[9],  (const float*)d_in[17]};
    const float* nb1[2] = {(const float*)d_in[10], (const float*)d_in[18]};
    const float* ow = (const float*)d_in[19];
    const float* ob = (const float*)d_in[20];
    float* out = (float*)d_out;

    float* h    = (float*)d_ws;               // 6400 x 32 f32
    float* h2   = h + 204800;                 // 6400 x 32 f32
    float* U    = h2 + 204800;                // 6400 x 64 f32
    float* U2   = U + 409600;                 // 6400 x 64 f32
    _Float16* V  = (_Float16*)(U2 + 409600);  // 6400 x 64 f16
    _Float16* V2 = V + 409600;                // 6400 x 64 f16
    _Float16* PW = V2 + 409600;               // 2 x 4096 f16
    _Float16* W0H  = PW + 8192;               // 2 x 6144 f16 (node-L0, swizzled)
    _Float16* W1H  = W0H + 12288;             // 2 x 2048 f16 (node-L1, swizzled)
    _Float16* EW0H = W1H + 4096;              // 4096 f16 (step-1 U/V, swizzled)
    _Float16* OWH  = EW0H + 4096;             // 96 f16 (out, transposed)

    k_pre<<<1608, 256, 0, stream>>>(x, lin_w, lin_b, ew0[0], eb0[0], ew1[0], ew1[1],
                                    nw0[0], nw0[1], nw1[0], nw1[1], ew0[1], ow,
                                    h, U, V, PW, W0H, W1H, EW0H, OWH);
    k_edge<0><<<1600, 256, 0, stream>>>(h, U, V, ew0[0], PW, eb1[0],
                                        W0H, nb0[0], W1H, nb1[0],
                                        EW0H, eb0[1], h2, U2, V2, nullptr);
    k_edge<1><<<1600, 256, 0, stream>>>(h2, U2, V2, ew0[1], PW + 4096, eb1[1],
                                        W0H + 6144, nb0[1], W1H + 2048, nb1[1],
                                        OWH, ob, nullptr, nullptr, nullptr, out);
}